// Round 2
// baseline (333.608 us; speedup 1.0000x reference)
//
#include <hip/hip_runtime.h>
#include <hip/hip_bf16.h>
#include <stdint.h>

// GroupedLinear: y[b, g*256+o] = sum_i x[b, g*256+i] * W[g,o,i] + bias[g,o]
// B=8192, G=16, GIN=GOUT=256. fp32 in/out, bf16 MFMA compute.
//
// Memory-bound: ~272 MB compulsory HBM (~44 us @ 6.3 TB/s achievable).
// v2: barrier-free. The 16x16x32 A/B fragment layout (lane l: row/col=l&15,
// k=(l>>4)*8 contiguous) is directly loadable from row-major X and W[g] with
// 2x global_load_dwordx4 per lane. LDS staging only gave 2x in-block reuse,
// which L1/L2 already provide (FETCH_SIZE ~= compulsory). Dropping LDS removes
// both __syncthreads per K-step (the vmcnt(0) drain was the latency wall) and
// lets each wave keep ~16 KB of loads in flight independently.

#define IN_F   4096
#define OUT_F  4096
#define GIN    256
#define GOUT   256

using short8  = __attribute__((ext_vector_type(8))) short;
using floatx4 = __attribute__((ext_vector_type(4))) float;

// round-to-nearest-even fp32 -> bf16 (branch-free)
__device__ __forceinline__ short f2bf_rne(float f) {
    unsigned u = __builtin_bit_cast(unsigned, f);
    unsigned r = u + 0x7FFFu + ((u >> 16) & 1u);
    return (short)(r >> 16);
}

// 8x fp32 -> 8x bf16 (RNE)
__device__ __forceinline__ short8 pack8(floatx4 f0, floatx4 f1) {
    short8 p;
    p[0] = f2bf_rne(f0[0]); p[1] = f2bf_rne(f0[1]);
    p[2] = f2bf_rne(f0[2]); p[3] = f2bf_rne(f0[3]);
    p[4] = f2bf_rne(f1[0]); p[5] = f2bf_rne(f1[1]);
    p[6] = f2bf_rne(f1[2]); p[7] = f2bf_rne(f1[3]);
    return p;
}

__global__ __launch_bounds__(256, 2)
void grouped_linear_kernel(const float* __restrict__ X,
                           const float* __restrict__ W,
                           const float* __restrict__ Bias,
                           float* __restrict__ Out) {
    const int t    = threadIdx.x;
    const int lane = t & 63;
    const int wave = t >> 6;
    const int wm   = wave >> 1;     // wave row (0..1) -> 64 rows
    const int wn   = wave & 1;      // wave col (0..1) -> 64 cols
    const int lrow = lane & 15;
    const int quad = lane >> 4;     // 0..3
    const int koff = quad * 8;      // k offset inside a 32-wide K step

    // XCD-aware swizzle: 2048 blocks, 8 XCDs, 256 blocks/XCD. Each XCD gets
    // 8 contiguous bm panels x all 32 bn, so the bn-pair sharing an X panel
    // (and all W[g] re-readers) hit the same XCD L2.
    const int bid = blockIdx.x;
    const int swz = (bid & 7) * 256 + (bid >> 3);
    const int bn  = swz & 31;           // 32 col-tiles of 128
    const int bm  = swz >> 5;           // 64 row-tiles of 128
    const int g   = bn >> 1;            // group (2 col-tiles per group)
    const int row0 = bm * 128 + wm * 64;            // this wave's global row base
    const int coln = (bn & 1) * 128 + wn * 64;      // col base inside group

    // Fragment base pointers: lane l covers row/col (base + l&15), k = koff..+7
    const float* pa[4];
    const float* pb[4];
    #pragma unroll
    for (int i = 0; i < 4; ++i)
        pa[i] = X + (size_t)(row0 + i * 16 + lrow) * IN_F + g * GIN + koff;
    #pragma unroll
    for (int j = 0; j < 4; ++j)
        pb[j] = W + (size_t)g * GOUT * GIN + (size_t)(coln + j * 16 + lrow) * GIN + koff;

    floatx4 acc[4][4];
    #pragma unroll
    for (int i = 0; i < 4; ++i)
        #pragma unroll
        for (int j = 0; j < 4; ++j)
            acc[i][j] = (floatx4){0.f, 0.f, 0.f, 0.f};

    // K = 256 = 8 steps of 32. Fully unrolled: all addressing folds into
    // saddr+voffset+imm, compiler pipelines loads across steps.
    #pragma unroll
    for (int ks = 0; ks < 8; ++ks) {
        short8 a[4], b[4];
        #pragma unroll
        for (int i = 0; i < 4; ++i) {
            floatx4 f0 = *(const floatx4*)(pa[i] + ks * 32);
            floatx4 f1 = *(const floatx4*)(pa[i] + ks * 32 + 4);
            a[i] = pack8(f0, f1);
        }
        #pragma unroll
        for (int j = 0; j < 4; ++j) {
            floatx4 f0 = *(const floatx4*)(pb[j] + ks * 32);
            floatx4 f1 = *(const floatx4*)(pb[j] + ks * 32 + 4);
            b[j] = pack8(f0, f1);
        }
        #pragma unroll
        for (int i = 0; i < 4; ++i)
            #pragma unroll
            for (int j = 0; j < 4; ++j)
                acc[i][j] = __builtin_amdgcn_mfma_f32_16x16x32_bf16(
                    a[i], b[j], acc[i][j], 0, 0, 0);
    }

    // Epilogue: C/D layout col=lane&15, row=quad*4+reg. Order stores so the
    // 4 j-stores of one row are back-to-back (64 contiguous cols per 16 lanes)
    // for write combining in L2.
    float bias[4];
    #pragma unroll
    for (int j = 0; j < 4; ++j)
        bias[j] = Bias[g * GOUT + coln + j * 16 + lrow];

    #pragma unroll
    for (int i = 0; i < 4; ++i) {
        #pragma unroll
        for (int rg = 0; rg < 4; ++rg) {
            size_t rowoff = (size_t)(row0 + i * 16 + quad * 4 + rg) * OUT_F;
            #pragma unroll
            for (int j = 0; j < 4; ++j)
                Out[rowoff + g * GOUT + coln + j * 16 + lrow] = acc[i][j][rg] + bias[j];
        }
    }
}

extern "C" void kernel_launch(void* const* d_in, const int* in_sizes, int n_in,
                              void* d_out, int out_size, void* d_ws, size_t ws_size,
                              hipStream_t stream) {
    const float* X    = (const float*)d_in[0];   // [8192, 4096]
    const float* W    = (const float*)d_in[1];   // [16, 256, 256]
    const float* Bias = (const float*)d_in[2];   // [16, 256]
    float*       Out  = (float*)d_out;           // [8192, 4096]

    dim3 grid(64 * 32);   // 64 M-tiles x 32 N-tiles
    dim3 block(256);
    grouped_linear_kernel<<<grid, block, 0, stream>>>(X, W, Bias, Out);
}

// Round 4
// 257.075 us; speedup vs baseline: 1.2977x; 1.2977x over previous
//
#include <hip/hip_runtime.h>
#include <stdint.h>

// GroupedLinear: y[b, g*256+o] = sum_i x[b, g*256+i] * W[g,o,i] + bias[g,o]
// B=8192, G=16, GIN=GOUT=256. fp32 in/out, bf16 MFMA compute.
//
// ~272 MB compulsory HBM -> ~43 us floor @ 6.3 TB/s. Round-0 (100 us) was
// latency-bound: coalesced staged loads, but zero bytes in flight during
// cvt/ds_write/__syncthreads(vmcnt-drain)/MFMA. Round-2 (176 us) proved
// fragment-direct loads die on coalescing (16 lines/instr).
// v3: round-0 staging + dbuf LDS + reg-prefetch + RAW s_barrier with
// lgkmcnt(0)-only waits -> next tile's 16 dwordx4/thread stay in flight
// across the barrier and the whole compute phase (T3/T4/T14).

#define IN_F   4096
#define OUT_F  4096
#define GIN    256
#define GOUT   256

#define BM 128
#define BN 128
#define BK 64
#define KTOT 256

using short8  = __attribute__((ext_vector_type(8))) short;
using floatx4 = __attribute__((ext_vector_type(4))) float;

// round-to-nearest-even fp32 -> bf16 (branch-free)
__device__ __forceinline__ short f2bf_rne(float f) {
    unsigned u = __builtin_bit_cast(unsigned, f);
    unsigned r = u + 0x7FFFu + ((u >> 16) & 1u);
    return (short)(r >> 16);
}

__device__ __forceinline__ short8 pack8(floatx4 f0, floatx4 f1) {
    short8 p;
    p[0] = f2bf_rne(f0[0]); p[1] = f2bf_rne(f0[1]);
    p[2] = f2bf_rne(f0[2]); p[3] = f2bf_rne(f0[3]);
    p[4] = f2bf_rne(f1[0]); p[5] = f2bf_rne(f1[1]);
    p[6] = f2bf_rne(f1[2]); p[7] = f2bf_rne(f1[3]);
    return p;
}

// writer-side sync: drain own ds_writes (lgkm only -- global prefetch loads
// stay in flight, THE point of this kernel), then raw barrier.
// sched_barrier(0) fences per guide rule #18 (hipcc hoists past asm waitcnt).
#define SYNC_PHASE() do {                                        \
    asm volatile("s_waitcnt lgkmcnt(0)" ::: "memory");           \
    __builtin_amdgcn_sched_barrier(0);                           \
    __builtin_amdgcn_s_barrier();                                \
    __builtin_amdgcn_sched_barrier(0);                           \
} while (0)

__global__ __launch_bounds__(256, 2)
void grouped_linear_kernel(const float* __restrict__ X,
                           const float* __restrict__ W,
                           const float* __restrict__ Bias,
                           float* __restrict__ Out) {
    // bf16 LDS tiles, XOR-swizzled in 8-elem (16B) chunks: chunk q of row r
    // at q ^ (r&7) -> 2-way bank aliasing max (free) for both ds_write_b128
    // and fragment ds_read_b128. Double-buffered: 64 KB total, 2 blocks/CU.
    __shared__ __align__(16) short lsA[2][BM * BK];   // 2 x 16 KB
    __shared__ __align__(16) short lsB[2][BN * BK];   // 2 x 16 KB

    const int t    = threadIdx.x;
    const int lane = t & 63;
    const int wave = t >> 6;
    const int wm   = wave >> 1;     // wave row (0..1) -> 64 rows
    const int wn   = wave & 1;      // wave col (0..1) -> 64 cols
    const int lrow = lane & 15;
    const int quad = lane >> 4;     // 0..3

    const int bn   = blockIdx.x & 31;   // 32 col-tiles of 128
    const int bm   = blockIdx.x >> 5;   // 64 row-tiles of 128
    const int g    = bn >> 1;           // group (2 col-tiles per group)
    const int row0 = bm * BM;
    const int col0 = bn * BN;
    const int nlb  = (bn & 1) * BN;     // N offset inside this group's W

    const float* Wg = W + (size_t)g * GOUT * GIN + (size_t)nlb * GIN;
    const float* Xg = X + (size_t)row0 * IN_F + g * GIN;

    floatx4 acc[4][4];
    #pragma unroll
    for (int i = 0; i < 4; ++i)
        #pragma unroll
        for (int j = 0; j < 4; ++j)
            acc[i][j] = (floatx4){0.f, 0.f, 0.f, 0.f};

    // staging geometry: thread covers rows r0+32i, 8 consecutive floats at c8.
    // 8 threads span one 64-float K-slice -> fully coalesced 32B/lane.
    const int c8 = (t & 7) * 8;
    const int q0 = (t & 7);
    const int r0 = (t >> 3);

    floatx4 ra[4][2], rb[4][2];     // prefetch registers (64 VGPR)

    // ---- issue 16 global_load_dwordx4 for K-tile kt into regs ----
    auto LOADS = [&](int kt) {
        const int kbase = kt * BK;
        #pragma unroll
        for (int i = 0; i < 4; ++i) {
            const float* src = Xg + (size_t)(r0 + 32 * i) * IN_F + kbase + c8;
            ra[i][0] = *(const floatx4*)src;
            ra[i][1] = *(const floatx4*)(src + 4);
        }
        #pragma unroll
        for (int i = 0; i < 4; ++i) {
            const float* src = Wg + (size_t)(r0 + 32 * i) * GIN + kbase + c8;
            rb[i][0] = *(const floatx4*)src;
            rb[i][1] = *(const floatx4*)(src + 4);
        }
    };

    // ---- cvt staged regs -> bf16, swizzled ds_write into buffer `buf` ----
    auto WRITE = [&](int buf) {
        #pragma unroll
        for (int i = 0; i < 4; ++i) {
            int r = r0 + 32 * i;
            int q = q0 ^ (r & 7);
            *(short8*)&lsA[buf][r * BK + q * 8] = pack8(ra[i][0], ra[i][1]);
        }
        #pragma unroll
        for (int i = 0; i < 4; ++i) {
            int n = r0 + 32 * i;
            int q = q0 ^ (n & 7);
            *(short8*)&lsB[buf][n * BK + q * 8] = pack8(rb[i][0], rb[i][1]);
        }
    };

    // ---- 32 MFMA from buffer `buf` ----
    auto COMPUTE = [&](int buf) {
        #pragma unroll
        for (int kk = 0; kk < 2; ++kk) {
            int kb = kk * 32 + quad * 8;
            int qs = kb >> 3;
            short8 a[4], b[4];
            #pragma unroll
            for (int i = 0; i < 4; ++i) {
                int r = wm * 64 + i * 16 + lrow;
                a[i] = *(const short8*)&lsA[buf][r * BK + ((qs ^ (r & 7)) * 8)];
            }
            #pragma unroll
            for (int j = 0; j < 4; ++j) {
                int n = wn * 64 + j * 16 + lrow;
                b[j] = *(const short8*)&lsB[buf][n * BK + ((qs ^ (n & 7)) * 8)];
            }
            #pragma unroll
            for (int i = 0; i < 4; ++i)
                #pragma unroll
                for (int j = 0; j < 4; ++j)
                    acc[i][j] = __builtin_amdgcn_mfma_f32_16x16x32_bf16(
                        a[i], b[j], acc[i][j], 0, 0, 0);
        }
    };

    // Pipeline (KTOT/BK = 4 tiles). Hazard audit:
    //  - WRITE(b0,kt2) comes after barrier#2 which follows every thread's
    //    COMPUTE(b0,kt0)  -> no read-after-overwrite.
    //  - WRITE(b1,kt3) comes after barrier#3 which follows every thread's
    //    COMPUTE(b1,kt1) -> safe.
    //  - reader visibility: writer drains lgkmcnt(0) before each barrier.
    //  - global loads are NEVER vmcnt-drained at a barrier; WRITE's cvt uses
    //    force the (needed-anyway) waits, later tiles stay in flight.
    LOADS(0);
    WRITE(0);
    LOADS(1);
    SYNC_PHASE();       // barrier 1: buf0 ready
    COMPUTE(0);         // kt0
    WRITE(1);           // kt1 (regs in flight since before barrier 1)
    LOADS(2);
    SYNC_PHASE();       // barrier 2: buf1 ready
    COMPUTE(1);         // kt1
    WRITE(0);           // kt2
    LOADS(3);
    SYNC_PHASE();       // barrier 3: buf0 ready
    COMPUTE(0);         // kt2
    WRITE(1);           // kt3
    SYNC_PHASE();       // barrier 4: buf1 ready
    COMPUTE(1);         // kt3

    // ---- epilogue: C/D layout col=lane&15, row=quad*4+reg; add bias ----
    #pragma unroll
    for (int j = 0; j < 4; ++j) {
        int gc = col0 + wn * 64 + j * 16 + lrow;
        float bias = Bias[gc];
        #pragma unroll
        for (int i = 0; i < 4; ++i) {
            int gr = row0 + wm * 64 + i * 16 + quad * 4;
            floatx4 v = acc[i][j];
            #pragma unroll
            for (int rg = 0; rg < 4; ++rg)
                Out[(size_t)(gr + rg) * OUT_F + gc] = v[rg] + bias;
        }
    }
}

extern "C" void kernel_launch(void* const* d_in, const int* in_sizes, int n_in,
                              void* d_out, int out_size, void* d_ws, size_t ws_size,
                              hipStream_t stream) {
    const float* X    = (const float*)d_in[0];   // [8192, 4096]
    const float* W    = (const float*)d_in[1];   // [16, 256, 256]
    const float* Bias = (const float*)d_in[2];   // [16, 256]
    float*       Out  = (float*)d_out;           // [8192, 4096]

    dim3 grid(64 * 32);   // 64 M-tiles x 32 N-tiles
    dim3 block(256);
    grouped_linear_kernel<<<grid, block, 0, stream>>>(X, W, Bias, Out);
}